// Round 10
// baseline (374.030 us; speedup 1.0000x reference)
//
#include <hip/hip_runtime.h>

typedef __bf16 bf16;
typedef __bf16 b16x8 __attribute__((ext_vector_type(8)));
typedef __bf16 b16x4 __attribute__((ext_vector_type(4)));
typedef float  f32x4 __attribute__((ext_vector_type(4)));

#define BN_TOT 1200
#define PROWS  1216    // padded row count (multiple of 64)
#define NCOL   53248   // G*(PW+SP) = 4*13312
#define QD     256

// ---------------------------------------------------------------------------
// K_pre: fused preprocessing, blockIdx-partitioned (R6-verbatim):
//   [0,512)   : W_v transpose -> WvT bf16
//   [512,664) : query f32 -> bf16 padded to 1216 rows
//   [664,814) : mb = query @ W_bias + b_bias
// ---------------------------------------------------------------------------
__global__ __launch_bounds__(256) void k_pre(const float* __restrict__ Wv,
                                             bf16* __restrict__ WvT,
                                             const float* __restrict__ qry,
                                             bf16* __restrict__ qbf,
                                             const float* __restrict__ Wb,
                                             const float* __restrict__ bb,
                                             float* __restrict__ mbo) {
  const int b = blockIdx.x;
  const int tid = threadIdx.x;
  if (b < 512) {
    __shared__ float t[64][65];
    const int kb = (b & 127) * 64, cb = (b >> 7) * 64;
    for (int i = 0; i < 16; ++i) {
      int idx = i * 256 + tid;
      int kk = idx >> 6, cc = idx & 63;
      t[kk][cc] = Wv[(size_t)(kb + kk) * 256 + cb + cc];
    }
    __syncthreads();
    for (int i = 0; i < 16; ++i) {
      int idx = i * 256 + tid;
      int cc = idx >> 6, kk = idx & 63;
      WvT[(size_t)(cb + cc) * 8192 + kb + kk] = (bf16)t[kk][cc];
    }
  } else if (b < 664) {
    int gid = (b - 512) * 256 + tid;
    int base = gid * 8;
    int row = base >> 8;
    b16x8 o;
#pragma unroll
    for (int i = 0; i < 8; ++i) o[i] = (bf16)0.f;
    if (row < BN_TOT) {
      float4 a0 = *(const float4*)&qry[base];
      float4 a1 = *(const float4*)&qry[base + 4];
      o[0] = (bf16)a0.x; o[1] = (bf16)a0.y; o[2] = (bf16)a0.z; o[3] = (bf16)a0.w;
      o[4] = (bf16)a1.x; o[5] = (bf16)a1.y; o[6] = (bf16)a1.z; o[7] = (bf16)a1.w;
    }
    *(b16x8*)&qbf[base] = o;
  } else {
    const int bn0 = (b - 664) * 8;
    const int j1 = tid;
    const int j2 = 256 + (tid & 127);
    float a1[8] = {}, a2[8] = {};
    for (int q = 0; q < 256; ++q) {
      float w1 = Wb[(size_t)q * 384 + j1];
      float w2 = Wb[(size_t)q * 384 + j2];
#pragma unroll
      for (int i = 0; i < 8; ++i) {
        float qv = qry[(size_t)(bn0 + i) * 256 + q];
        a1[i] += qv * w1; a2[i] += qv * w2;
      }
    }
    float b1 = bb[j1], b2 = bb[j2];
#pragma unroll
    for (int i = 0; i < 8; ++i) mbo[(size_t)(bn0 + i) * 384 + j1] = a1[i] + b1;
    if (tid < 128)
#pragma unroll
      for (int i = 0; i < 8; ++i) mbo[(size_t)(bn0 + i) * 384 + j2] = a2[i] + b2;
  }
}

// ---------------------------------------------------------------------------
// K1: P = bf16(query @ W_gen + b_gen)   (1216 x 53248, K=256)
// R8-verbatim: B-fragments direct from global Wg (sync-free); A-path
// double-buffered global_load_lds pipeline (64 KB LDS, one barrier per rc).
// ---------------------------------------------------------------------------
__global__ __launch_bounds__(256) void k_params(const bf16* __restrict__ qbf,
                                                const float* __restrict__ Wg,
                                                const float* __restrict__ bg,
                                                bf16* __restrict__ P) {
  __shared__ __align__(16) bf16 lds[2 * 64 * 256];   // 64 KB A double-buffer

  const int tid  = threadIdx.x;
  const int col0 = blockIdx.x * 128;
  const int wave = tid >> 6, lane = tid & 63;
  const int l15  = lane & 15, lhi = lane >> 4;

  // B fragments + bias, straight from global (one-time, no LDS, no sync)
  b16x8 bfrag[2][8];
  float bcol[2];
#pragma unroll
  for (int nt = 0; nt < 2; ++nt) {
    int col = col0 + wave * 32 + nt * 16 + l15;
#pragma unroll
    for (int kk = 0; kk < 8; ++kk)
#pragma unroll
      for (int j = 0; j < 8; ++j)
        bfrag[nt][kk][j] = (bf16)Wg[(size_t)(kk * 32 + lhi * 8 + j) * NCOL + col];
    bcol[nt] = bg[col];
  }

  // ---- K-loop over 19 row-tiles ----
  const char* qb = (const char*)qbf;
#define STAGE_A(b, rc)                                                         \
  {                                                                            \
    const char* s0 = qb + (size_t)(rc) * 64 * 512;                             \
    _Pragma("unroll")                                                          \
    for (int i = 0; i < 8; ++i) {                                              \
      int c = i * 256 + wave * 64 + lane;                                      \
      int r = c >> 5;                                                          \
      int boff = ((c & 31) << 4) ^ ((r & 7) << 4);                             \
      const void* src = (const void*)(s0 + r * 512 + boff);                    \
      bf16* dst = &lds[(b) * 16384 + (size_t)(i * 256 + wave * 64) * 8];       \
      __builtin_amdgcn_global_load_lds(                                        \
          (const __attribute__((address_space(1))) void*)src,                  \
          (__attribute__((address_space(3))) void*)dst, 16, 0, 0);             \
    }                                                                          \
  }

  STAGE_A(0, 0);
  __syncthreads();   // drain prologue staging

  for (int rc = 0; rc < 19; ++rc) {
    int cur = rc & 1;
    if (rc + 1 < 19) STAGE_A(cur ^ 1, rc + 1);   // prefetch flies under compute

    const bf16* At = &lds[cur * 16384];
    int r0 = rc * 64;
    f32x4 acc[4][2] = {};
#pragma unroll
    for (int kk = 0; kk < 8; ++kk)
#pragma unroll
      for (int mt = 0; mt < 4; ++mt) {
        int row = mt * 16 + l15;
        int coff = (kk * 32 + lhi * 8) ^ ((l15 & 7) << 3);
        b16x8 af = *(const b16x8*)&At[row * 256 + coff];
        acc[mt][0] = __builtin_amdgcn_mfma_f32_16x16x32_bf16(af, bfrag[0][kk], acc[mt][0], 0, 0, 0);
        acc[mt][1] = __builtin_amdgcn_mfma_f32_16x16x32_bf16(af, bfrag[1][kk], acc[mt][1], 0, 0, 0);
      }
#pragma unroll
    for (int mt = 0; mt < 4; ++mt) {
      int rbase = r0 + mt * 16 + lhi * 4;
#pragma unroll
      for (int nt = 0; nt < 2; ++nt) {
        size_t cg = (size_t)col0 + wave * 32 + nt * 16 + l15;
        bf16* pp = &P[(size_t)rbase * NCOL + cg];
#pragma unroll
        for (int r = 0; r < 4; ++r)
          pp[(size_t)r * NCOL] = (bf16)(acc[mt][nt][r] + bcol[nt]);
      }
    }
    __syncthreads();   // prefetch complete + buffer safe to overwrite
  }
#undef STAGE_A
}

// ---------------------------------------------------------------------------
// K2: per-(bn,g) cascade mix. R9-verbatim body.
// MEASUREMENT PROBE this round: launched TWICE (see kernel_launch) — the
// second launch recomputes identical H bytes (pure function, no RMW, no
// race across sequential dispatches). dur_R10 - dur_R9 ~= k_mix duration.
// ---------------------------------------------------------------------------
__global__ __launch_bounds__(256, 4) void k_mix(const float* __restrict__ x,
                                                const bf16* __restrict__ P,
                                                const float* __restrict__ mb,
                                                bf16* __restrict__ H) {
  __shared__ __align__(16) bf16 h1T[64 * 296];   // [d][p], 37.9 KB

  const int blk = blockIdx.x;
  const int bn = blk >> 2, g = blk & 3;
  const int tid = threadIdx.x;
  const int wave = tid >> 6, lane = tid & 63;
  const int l15 = lane & 15, lhi = lane >> 4;

  const size_t pb = (size_t)bn * NCOL + g * 13312;
  const float* mbp = mb + (size_t)bn * 384 + g * 96;

  // M fragments (B-operand [k=c][n=d]) direct from P, scalar gather
  b16x8 mfrag[4][2];
  float mbv[4];
#pragma unroll
  for (int nt = 0; nt < 4; ++nt) {
    int d = nt * 16 + l15;
    mbv[nt] = mbp[d];
#pragma unroll
    for (int kk = 0; kk < 2; ++kk) {
      const bf16* mp = &P[pb + (size_t)(kk * 32 + lhi * 8) * 64 + d];
#pragma unroll
      for (int j = 0; j < 8; ++j) mfrag[nt][kk][j] = mp[(size_t)j * 64];
    }
  }

  // S fragments prefetched now (independent of h1)
  const int mt2 = wave >> 1;
  const int ntb = (wave & 1) * 2;
  const bf16* Sp = &P[pb + 4096];
  b16x8 sfrag[9];
#pragma unroll
  for (int kk = 0; kk < 9; ++kk)
    sfrag[kk] = *(const b16x8*)&Sp[(size_t)(mt2 * 16 + l15) * 288 + kk * 32 + lhi * 8];

  // MFMA1: h1 = relu(x @ M * 0.125 + M_b), A = x streamed from HBM
  const float* xp0 = &x[((size_t)bn * 4 + g) * 18432];
#pragma unroll
  for (int m0 = 0; m0 < 5; ++m0) {
    int mt = wave + m0 * 4;
    if (mt < 18) {
      f32x4 acc[4] = {};
#pragma unroll
      for (int kk = 0; kk < 2; ++kk) {
        const float* xp = xp0 + (mt * 16 + l15) * 64 + kk * 32 + lhi * 8;
        float4 a0 = *(const float4*)xp;
        float4 a1 = *(const float4*)(xp + 4);
        b16x8 af;
        af[0] = (bf16)a0.x; af[1] = (bf16)a0.y; af[2] = (bf16)a0.z; af[3] = (bf16)a0.w;
        af[4] = (bf16)a1.x; af[5] = (bf16)a1.y; af[6] = (bf16)a1.z; af[7] = (bf16)a1.w;
#pragma unroll
        for (int nt = 0; nt < 4; ++nt)
          acc[nt] = __builtin_amdgcn_mfma_f32_16x16x32_bf16(af, mfrag[nt][kk], acc[nt], 0, 0, 0);
      }
#pragma unroll
      for (int nt = 0; nt < 4; ++nt) {
        int d = nt * 16 + l15;
        b16x4 hv;
#pragma unroll
        for (int r = 0; r < 4; ++r) {
          float v = acc[nt][r] * 0.125f + mbv[nt];   // /TEMPER then +M_b
          hv[r] = (bf16)(v > 0.f ? v : 0.f);
        }
        *(b16x4*)&h1T[d * 296 + mt * 16 + lhi * 4] = hv;
      }
    }
  }
  __syncthreads();

  // S_b gathered here: consumed only at the H-store, latency hides under MFMA2
  float sbv[4];
#pragma unroll
  for (int r = 0; r < 4; ++r) sbv[r] = mbp[64 + mt2 * 16 + lhi * 4 + r];

  // MFMA2: h2 = relu(S @ h1 + S_b), S already in registers
  f32x4 acc2[2] = {};
#pragma unroll
  for (int kk = 0; kk < 9; ++kk) {
#pragma unroll
    for (int t = 0; t < 2; ++t) {
      b16x8 bfv = *(const b16x8*)&h1T[((ntb + t) * 16 + l15) * 296 + kk * 32 + lhi * 8];
      acc2[t] = __builtin_amdgcn_mfma_f32_16x16x32_bf16(sfrag[kk], bfv, acc2[t], 0, 0, 0);
    }
  }
  bf16* Hp = H + (size_t)bn * 8192 + g * 64;       // H[bn][o][g][c]
#pragma unroll
  for (int r = 0; r < 4; ++r) {
    int o = mt2 * 16 + lhi * 4 + r;
#pragma unroll
    for (int t = 0; t < 2; ++t) {
      float v = acc2[t][r] + sbv[r];
      Hp[o * 256 + (ntb + t) * 16 + l15] = (bf16)(v > 0.f ? v : 0.f);
    }
  }
}

// ---------------------------------------------------------------------------
// K3: part[kz] = H[:, kz*512:+512] @ W_vT^T   (split-K=16, fp32 partials)
// R6-verbatim: LDS-free, sync-free.
// ---------------------------------------------------------------------------
__global__ __launch_bounds__(256) void k_out(const bf16* __restrict__ H,
                                             const bf16* __restrict__ WvT,
                                             float* __restrict__ part) {
  const int tid = threadIdx.x;
  const int wave = tid >> 6, lane = tid & 63;
  const int l15 = lane & 15, lhi = lane >> 4;
  const int r0 = blockIdx.x * 64;
  const int k0 = blockIdx.y * 512;

  f32x4 acc[4][4] = {};
  for (int it = 0; it < 8; ++it) {
    int kb = k0 + it * 64;
    b16x8 bfv[2][4], afv[2][4];
#pragma unroll
    for (int kk = 0; kk < 2; ++kk)
#pragma unroll
      for (int nt = 0; nt < 4; ++nt)
        bfv[kk][nt] = *(const b16x8*)&WvT[(size_t)(wave * 64 + nt * 16 + l15) * 8192 + kb + kk * 32 + lhi * 8];
#pragma unroll
    for (int kk = 0; kk < 2; ++kk)
#pragma unroll
      for (int mt = 0; mt < 4; ++mt)
        afv[kk][mt] = *(const b16x8*)&H[(size_t)(r0 + mt * 16 + l15) * 8192 + kb + kk * 32 + lhi * 8];
#pragma unroll
    for (int kk = 0; kk < 2; ++kk)
#pragma unroll
      for (int mt = 0; mt < 4; ++mt)
#pragma unroll
        for (int nt = 0; nt < 4; ++nt)
          acc[mt][nt] = __builtin_amdgcn_mfma_f32_16x16x32_bf16(afv[kk][mt], bfv[kk][nt], acc[mt][nt], 0, 0, 0);
  }
  const size_t pbase = (size_t)blockIdx.y * PROWS * 256;
#pragma unroll
  for (int mt = 0; mt < 4; ++mt)
#pragma unroll
    for (int nt = 0; nt < 4; ++nt) {
      int col = wave * 64 + nt * 16 + l15;
#pragma unroll
      for (int r = 0; r < 4; ++r) {
        int row = r0 + mt * 16 + lhi * 4 + r;
        part[pbase + (size_t)row * 256 + col] = acc[mt][nt][r];
      }
    }
}

// ---------------------------------------------------------------------------
// K4: out = LayerNorm(sum_kz part + b_v) * ln_g + ln_b   (R6-verbatim)
// ---------------------------------------------------------------------------
__global__ __launch_bounds__(256) void k_ln(const float* __restrict__ part,
                                            const float* __restrict__ bv,
                                            const float* __restrict__ lng,
                                            const float* __restrict__ lnb,
                                            float* __restrict__ out) {
  __shared__ float red[8];
  const int row = blockIdx.x, c = threadIdx.x;
  const int wave = c >> 6, lane = c & 63;
  float v = bv[c];
  for (int kz = 0; kz < 16; ++kz)
    v += part[((size_t)kz * PROWS + row) * 256 + c];
  float s = v;
  for (int off = 32; off > 0; off >>= 1) s += __shfl_xor(s, off);
  if (lane == 0) red[wave] = s;
  __syncthreads();
  float mean = (red[0] + red[1] + red[2] + red[3]) * (1.0f / 256.0f);
  float d = v - mean;
  float q = d * d;
  for (int off = 32; off > 0; off >>= 1) q += __shfl_xor(q, off);
  if (lane == 0) red[4 + wave] = q;
  __syncthreads();
  float var = (red[4] + red[5] + red[6] + red[7]) * (1.0f / 256.0f);
  out[(size_t)row * 256 + c] = d * rsqrtf(var + 1e-5f) * lng[c] + lnb[c];
}

// ---------------------------------------------------------------------------
extern "C" void kernel_launch(void* const* d_in, const int* in_sizes, int n_in,
                              void* d_out, int out_size, void* d_ws, size_t ws_size,
                              hipStream_t stream) {
  const float* x   = (const float*)d_in[0];
  const float* qry = (const float*)d_in[1];
  const float* Wg  = (const float*)d_in[2];
  const float* bg  = (const float*)d_in[3];
  const float* Wb  = (const float*)d_in[4];
  const float* bb  = (const float*)d_in[5];
  const float* Wv  = (const float*)d_in[6];
  const float* bv  = (const float*)d_in[7];
  const float* lng = (const float*)d_in[8];
  const float* lnb = (const float*)d_in[9];
  float* out = (float*)d_out;

  // ws layout (bytes):
  char* ws = (char*)d_ws;
  bf16*  P    = (bf16*) (ws + 0);           // params bf16: 1216*53248*2 = 129,499,136
  bf16*  H    = (bf16*) (ws + 129499136);   // h2 bf16:     1216*8192*2  = 19,922,944
  float* mbw  = (float*)(ws + 149422080);   // mix bias:    1200*384*4   = 1,843,200
  bf16*  WvT  = (bf16*) (ws + 151265280);   // W_v^T bf16:  256*8192*2   = 4,194,304
  float* part = (float*)(ws + 155459584);   // splitK:      16*1216*256*4 = 19,922,944
  bf16*  qbf  = (bf16*) (ws + 155459584);   // aliased over part (dead before k_out)

  k_pre<<<814, 256, 0, stream>>>(Wv, WvT, qry, qbf, Wb, bb, mbw);
  k_params<<<416, 256, 0, stream>>>(qbf, Wg, bg, P);
  k_mix<<<4800, 256, 0, stream>>>(x, P, mbw, H);
  // MEASUREMENT PROBE: duplicate k_mix launch (idempotent; writes identical
  // bytes). dur_R10 - dur_R9 isolates k_mix's duration. Remove next round.
  k_mix<<<4800, 256, 0, stream>>>(x, P, mbw, H);
  k_out<<<dim3(19, 16), 256, 0, stream>>>(H, WvT, part);
  k_ln<<<1200, 256, 0, stream>>>(part, bv, lng, lnb, out);
}

// Round 11
// 322.159 us; speedup vs baseline: 1.1610x; 1.1610x over previous
//
#include <hip/hip_runtime.h>

typedef __bf16 bf16;
typedef __bf16 b16x8 __attribute__((ext_vector_type(8)));
typedef __bf16 b16x4 __attribute__((ext_vector_type(4)));
typedef float  f32x4 __attribute__((ext_vector_type(4)));

#define BN_TOT 1200
#define PROWS  1216    // padded row count (multiple of 64)
#define NCOL   53248   // G*(PW+SP) = 4*13312
#define QD     256

// ---------------------------------------------------------------------------
// K_pre: fused preprocessing, blockIdx-partitioned (R6-verbatim):
//   [0,512)   : W_v transpose -> WvT bf16
//   [512,664) : query f32 -> bf16 padded to 1216 rows
//   [664,814) : mb = query @ W_bias + b_bias
// ---------------------------------------------------------------------------
__global__ __launch_bounds__(256) void k_pre(const float* __restrict__ Wv,
                                             bf16* __restrict__ WvT,
                                             const float* __restrict__ qry,
                                             bf16* __restrict__ qbf,
                                             const float* __restrict__ Wb,
                                             const float* __restrict__ bb,
                                             float* __restrict__ mbo) {
  const int b = blockIdx.x;
  const int tid = threadIdx.x;
  if (b < 512) {
    __shared__ float t[64][65];
    const int kb = (b & 127) * 64, cb = (b >> 7) * 64;
    for (int i = 0; i < 16; ++i) {
      int idx = i * 256 + tid;
      int kk = idx >> 6, cc = idx & 63;
      t[kk][cc] = Wv[(size_t)(kb + kk) * 256 + cb + cc];
    }
    __syncthreads();
    for (int i = 0; i < 16; ++i) {
      int idx = i * 256 + tid;
      int cc = idx >> 6, kk = idx & 63;
      WvT[(size_t)(cb + cc) * 8192 + kb + kk] = (bf16)t[kk][cc];
    }
  } else if (b < 664) {
    int gid = (b - 512) * 256 + tid;
    int base = gid * 8;
    int row = base >> 8;
    b16x8 o;
#pragma unroll
    for (int i = 0; i < 8; ++i) o[i] = (bf16)0.f;
    if (row < BN_TOT) {
      float4 a0 = *(const float4*)&qry[base];
      float4 a1 = *(const float4*)&qry[base + 4];
      o[0] = (bf16)a0.x; o[1] = (bf16)a0.y; o[2] = (bf16)a0.z; o[3] = (bf16)a0.w;
      o[4] = (bf16)a1.x; o[5] = (bf16)a1.y; o[6] = (bf16)a1.z; o[7] = (bf16)a1.w;
    }
    *(b16x8*)&qbf[base] = o;
  } else {
    const int bn0 = (b - 664) * 8;
    const int j1 = tid;
    const int j2 = 256 + (tid & 127);
    float a1[8] = {}, a2[8] = {};
    for (int q = 0; q < 256; ++q) {
      float w1 = Wb[(size_t)q * 384 + j1];
      float w2 = Wb[(size_t)q * 384 + j2];
#pragma unroll
      for (int i = 0; i < 8; ++i) {
        float qv = qry[(size_t)(bn0 + i) * 256 + q];
        a1[i] += qv * w1; a2[i] += qv * w2;
      }
    }
    float b1 = bb[j1], b2 = bb[j2];
#pragma unroll
    for (int i = 0; i < 8; ++i) mbo[(size_t)(bn0 + i) * 384 + j1] = a1[i] + b1;
    if (tid < 128)
#pragma unroll
      for (int i = 0; i < 8; ++i) mbo[(size_t)(bn0 + i) * 384 + j2] = a2[i] + b2;
  }
}

// ---------------------------------------------------------------------------
// K1: P = bf16(query @ W_gen + b_gen)   (1216 x 53248, K=256)
// R8-verbatim. MEASUREMENT PROBE this round: launched TWICE (idempotent,
// pure function of qbf/Wg/bg). k_params ~= dur_R11 - dur_R9. Remove next.
// ---------------------------------------------------------------------------
__global__ __launch_bounds__(256) void k_params(const bf16* __restrict__ qbf,
                                                const float* __restrict__ Wg,
                                                const float* __restrict__ bg,
                                                bf16* __restrict__ P) {
  __shared__ __align__(16) bf16 lds[2 * 64 * 256];   // 64 KB A double-buffer

  const int tid  = threadIdx.x;
  const int col0 = blockIdx.x * 128;
  const int wave = tid >> 6, lane = tid & 63;
  const int l15  = lane & 15, lhi = lane >> 4;

  // B fragments + bias, straight from global (one-time, no LDS, no sync)
  b16x8 bfrag[2][8];
  float bcol[2];
#pragma unroll
  for (int nt = 0; nt < 2; ++nt) {
    int col = col0 + wave * 32 + nt * 16 + l15;
#pragma unroll
    for (int kk = 0; kk < 8; ++kk)
#pragma unroll
      for (int j = 0; j < 8; ++j)
        bfrag[nt][kk][j] = (bf16)Wg[(size_t)(kk * 32 + lhi * 8 + j) * NCOL + col];
    bcol[nt] = bg[col];
  }

  // ---- K-loop over 19 row-tiles ----
  const char* qb = (const char*)qbf;
#define STAGE_A(b, rc)                                                         \
  {                                                                            \
    const char* s0 = qb + (size_t)(rc) * 64 * 512;                             \
    _Pragma("unroll")                                                          \
    for (int i = 0; i < 8; ++i) {                                              \
      int c = i * 256 + wave * 64 + lane;                                      \
      int r = c >> 5;                                                          \
      int boff = ((c & 31) << 4) ^ ((r & 7) << 4);                             \
      const void* src = (const void*)(s0 + r * 512 + boff);                    \
      bf16* dst = &lds[(b) * 16384 + (size_t)(i * 256 + wave * 64) * 8];       \
      __builtin_amdgcn_global_load_lds(                                        \
          (const __attribute__((address_space(1))) void*)src,                  \
          (__attribute__((address_space(3))) void*)dst, 16, 0, 0);             \
    }                                                                          \
  }

  STAGE_A(0, 0);
  __syncthreads();   // drain prologue staging

  for (int rc = 0; rc < 19; ++rc) {
    int cur = rc & 1;
    if (rc + 1 < 19) STAGE_A(cur ^ 1, rc + 1);   // prefetch flies under compute

    const bf16* At = &lds[cur * 16384];
    int r0 = rc * 64;
    f32x4 acc[4][2] = {};
#pragma unroll
    for (int kk = 0; kk < 8; ++kk)
#pragma unroll
      for (int mt = 0; mt < 4; ++mt) {
        int row = mt * 16 + l15;
        int coff = (kk * 32 + lhi * 8) ^ ((l15 & 7) << 3);
        b16x8 af = *(const b16x8*)&At[row * 256 + coff];
        acc[mt][0] = __builtin_amdgcn_mfma_f32_16x16x32_bf16(af, bfrag[0][kk], acc[mt][0], 0, 0, 0);
        acc[mt][1] = __builtin_amdgcn_mfma_f32_16x16x32_bf16(af, bfrag[1][kk], acc[mt][1], 0, 0, 0);
      }
#pragma unroll
    for (int mt = 0; mt < 4; ++mt) {
      int rbase = r0 + mt * 16 + lhi * 4;
#pragma unroll
      for (int nt = 0; nt < 2; ++nt) {
        size_t cg = (size_t)col0 + wave * 32 + nt * 16 + l15;
        bf16* pp = &P[(size_t)rbase * NCOL + cg];
#pragma unroll
        for (int r = 0; r < 4; ++r)
          pp[(size_t)r * NCOL] = (bf16)(acc[mt][nt][r] + bcol[nt]);
      }
    }
    __syncthreads();   // prefetch complete + buffer safe to overwrite
  }
#undef STAGE_A
}

// ---------------------------------------------------------------------------
// K2: per-(bn,g) cascade mix. R9-verbatim body, single launch again.
// ---------------------------------------------------------------------------
__global__ __launch_bounds__(256, 4) void k_mix(const float* __restrict__ x,
                                                const bf16* __restrict__ P,
                                                const float* __restrict__ mb,
                                                bf16* __restrict__ H) {
  __shared__ __align__(16) bf16 h1T[64 * 296];   // [d][p], 37.9 KB

  const int blk = blockIdx.x;
  const int bn = blk >> 2, g = blk & 3;
  const int tid = threadIdx.x;
  const int wave = tid >> 6, lane = tid & 63;
  const int l15 = lane & 15, lhi = lane >> 4;

  const size_t pb = (size_t)bn * NCOL + g * 13312;
  const float* mbp = mb + (size_t)bn * 384 + g * 96;

  // M fragments (B-operand [k=c][n=d]) direct from P, scalar gather
  b16x8 mfrag[4][2];
  float mbv[4];
#pragma unroll
  for (int nt = 0; nt < 4; ++nt) {
    int d = nt * 16 + l15;
    mbv[nt] = mbp[d];
#pragma unroll
    for (int kk = 0; kk < 2; ++kk) {
      const bf16* mp = &P[pb + (size_t)(kk * 32 + lhi * 8) * 64 + d];
#pragma unroll
      for (int j = 0; j < 8; ++j) mfrag[nt][kk][j] = mp[(size_t)j * 64];
    }
  }

  // S fragments prefetched now (independent of h1)
  const int mt2 = wave >> 1;
  const int ntb = (wave & 1) * 2;
  const bf16* Sp = &P[pb + 4096];
  b16x8 sfrag[9];
#pragma unroll
  for (int kk = 0; kk < 9; ++kk)
    sfrag[kk] = *(const b16x8*)&Sp[(size_t)(mt2 * 16 + l15) * 288 + kk * 32 + lhi * 8];

  // MFMA1: h1 = relu(x @ M * 0.125 + M_b), A = x streamed from HBM
  const float* xp0 = &x[((size_t)bn * 4 + g) * 18432];
#pragma unroll
  for (int m0 = 0; m0 < 5; ++m0) {
    int mt = wave + m0 * 4;
    if (mt < 18) {
      f32x4 acc[4] = {};
#pragma unroll
      for (int kk = 0; kk < 2; ++kk) {
        const float* xp = xp0 + (mt * 16 + l15) * 64 + kk * 32 + lhi * 8;
        float4 a0 = *(const float4*)xp;
        float4 a1 = *(const float4*)(xp + 4);
        b16x8 af;
        af[0] = (bf16)a0.x; af[1] = (bf16)a0.y; af[2] = (bf16)a0.z; af[3] = (bf16)a0.w;
        af[4] = (bf16)a1.x; af[5] = (bf16)a1.y; af[6] = (bf16)a1.z; af[7] = (bf16)a1.w;
#pragma unroll
        for (int nt = 0; nt < 4; ++nt)
          acc[nt] = __builtin_amdgcn_mfma_f32_16x16x32_bf16(af, mfrag[nt][kk], acc[nt], 0, 0, 0);
      }
#pragma unroll
      for (int nt = 0; nt < 4; ++nt) {
        int d = nt * 16 + l15;
        b16x4 hv;
#pragma unroll
        for (int r = 0; r < 4; ++r) {
          float v = acc[nt][r] * 0.125f + mbv[nt];   // /TEMPER then +M_b
          hv[r] = (bf16)(v > 0.f ? v : 0.f);
        }
        *(b16x4*)&h1T[d * 296 + mt * 16 + lhi * 4] = hv;
      }
    }
  }
  __syncthreads();

  // S_b gathered here: consumed only at the H-store, latency hides under MFMA2
  float sbv[4];
#pragma unroll
  for (int r = 0; r < 4; ++r) sbv[r] = mbp[64 + mt2 * 16 + lhi * 4 + r];

  // MFMA2: h2 = relu(S @ h1 + S_b), S already in registers
  f32x4 acc2[2] = {};
#pragma unroll
  for (int kk = 0; kk < 9; ++kk) {
#pragma unroll
    for (int t = 0; t < 2; ++t) {
      b16x8 bfv = *(const b16x8*)&h1T[((ntb + t) * 16 + l15) * 296 + kk * 32 + lhi * 8];
      acc2[t] = __builtin_amdgcn_mfma_f32_16x16x32_bf16(sfrag[kk], bfv, acc2[t], 0, 0, 0);
    }
  }
  bf16* Hp = H + (size_t)bn * 8192 + g * 64;       // H[bn][o][g][c]
#pragma unroll
  for (int r = 0; r < 4; ++r) {
    int o = mt2 * 16 + lhi * 4 + r;
#pragma unroll
    for (int t = 0; t < 2; ++t) {
      float v = acc2[t][r] + sbv[r];
      Hp[o * 256 + (ntb + t) * 16 + l15] = (bf16)(v > 0.f ? v : 0.f);
    }
  }
}

// ---------------------------------------------------------------------------
// K3: part[kz] = H[:, kz*512:+512] @ W_vT^T   (split-K=16, fp32 partials)
// R6-verbatim: LDS-free, sync-free.
// ---------------------------------------------------------------------------
__global__ __launch_bounds__(256) void k_out(const bf16* __restrict__ H,
                                             const bf16* __restrict__ WvT,
                                             float* __restrict__ part) {
  const int tid = threadIdx.x;
  const int wave = tid >> 6, lane = tid & 63;
  const int l15 = lane & 15, lhi = lane >> 4;
  const int r0 = blockIdx.x * 64;
  const int k0 = blockIdx.y * 512;

  f32x4 acc[4][4] = {};
  for (int it = 0; it < 8; ++it) {
    int kb = k0 + it * 64;
    b16x8 bfv[2][4], afv[2][4];
#pragma unroll
    for (int kk = 0; kk < 2; ++kk)
#pragma unroll
      for (int nt = 0; nt < 4; ++nt)
        bfv[kk][nt] = *(const b16x8*)&WvT[(size_t)(wave * 64 + nt * 16 + l15) * 8192 + kb + kk * 32 + lhi * 8];
#pragma unroll
    for (int kk = 0; kk < 2; ++kk)
#pragma unroll
      for (int mt = 0; mt < 4; ++mt)
        afv[kk][mt] = *(const b16x8*)&H[(size_t)(r0 + mt * 16 + l15) * 8192 + kb + kk * 32 + lhi * 8];
#pragma unroll
    for (int kk = 0; kk < 2; ++kk)
#pragma unroll
      for (int mt = 0; mt < 4; ++mt)
#pragma unroll
        for (int nt = 0; nt < 4; ++nt)
          acc[mt][nt] = __builtin_amdgcn_mfma_f32_16x16x32_bf16(afv[kk][mt], bfv[kk][nt], acc[mt][nt], 0, 0, 0);
  }
  const size_t pbase = (size_t)blockIdx.y * PROWS * 256;
#pragma unroll
  for (int mt = 0; mt < 4; ++mt)
#pragma unroll
    for (int nt = 0; nt < 4; ++nt) {
      int col = wave * 64 + nt * 16 + l15;
#pragma unroll
      for (int r = 0; r < 4; ++r) {
        int row = r0 + mt * 16 + lhi * 4 + r;
        part[pbase + (size_t)row * 256 + col] = acc[mt][nt][r];
      }
    }
}

// ---------------------------------------------------------------------------
// K4: out = LayerNorm(sum_kz part + b_v) * ln_g + ln_b   (R6-verbatim)
// ---------------------------------------------------------------------------
__global__ __launch_bounds__(256) void k_ln(const float* __restrict__ part,
                                            const float* __restrict__ bv,
                                            const float* __restrict__ lng,
                                            const float* __restrict__ lnb,
                                            float* __restrict__ out) {
  __shared__ float red[8];
  const int row = blockIdx.x, c = threadIdx.x;
  const int wave = c >> 6, lane = c & 63;
  float v = bv[c];
  for (int kz = 0; kz < 16; ++kz)
    v += part[((size_t)kz * PROWS + row) * 256 + c];
  float s = v;
  for (int off = 32; off > 0; off >>= 1) s += __shfl_xor(s, off);
  if (lane == 0) red[wave] = s;
  __syncthreads();
  float mean = (red[0] + red[1] + red[2] + red[3]) * (1.0f / 256.0f);
  float d = v - mean;
  float q = d * d;
  for (int off = 32; off > 0; off >>= 1) q += __shfl_xor(q, off);
  if (lane == 0) red[4 + wave] = q;
  __syncthreads();
  float var = (red[4] + red[5] + red[6] + red[7]) * (1.0f / 256.0f);
  out[(size_t)row * 256 + c] = d * rsqrtf(var + 1e-5f) * lng[c] + lnb[c];
}

// ---------------------------------------------------------------------------
extern "C" void kernel_launch(void* const* d_in, const int* in_sizes, int n_in,
                              void* d_out, int out_size, void* d_ws, size_t ws_size,
                              hipStream_t stream) {
  const float* x   = (const float*)d_in[0];
  const float* qry = (const float*)d_in[1];
  const float* Wg  = (const float*)d_in[2];
  const float* bg  = (const float*)d_in[3];
  const float* Wb  = (const float*)d_in[4];
  const float* bb  = (const float*)d_in[5];
  const float* Wv  = (const float*)d_in[6];
  const float* bv  = (const float*)d_in[7];
  const float* lng = (const float*)d_in[8];
  const float* lnb = (const float*)d_in[9];
  float* out = (float*)d_out;

  // ws layout (bytes):
  char* ws = (char*)d_ws;
  bf16*  P    = (bf16*) (ws + 0);           // params bf16: 1216*53248*2 = 129,499,136
  bf16*  H    = (bf16*) (ws + 129499136);   // h2 bf16:     1216*8192*2  = 19,922,944
  float* mbw  = (float*)(ws + 149422080);   // mix bias:    1200*384*4   = 1,843,200
  bf16*  WvT  = (bf16*) (ws + 151265280);   // W_v^T bf16:  256*8192*2   = 4,194,304
  float* part = (float*)(ws + 155459584);   // splitK:      16*1216*256*4 = 19,922,944
  bf16*  qbf  = (bf16*) (ws + 155459584);   // aliased over part (dead before k_out)

  k_pre<<<814, 256, 0, stream>>>(Wv, WvT, qry, qbf, Wb, bb, mbw);
  k_params<<<416, 256, 0, stream>>>(qbf, Wg, bg, P);
  // MEASUREMENT PROBE: duplicate k_params launch (idempotent; writes
  // identical bytes). k_params ~= dur_R11 - dur_R9. Remove next round.
  k_params<<<416, 256, 0, stream>>>(qbf, Wg, bg, P);
  k_mix<<<4800, 256, 0, stream>>>(x, P, mbw, H);
  k_out<<<dim3(19, 16), 256, 0, stream>>>(H, WvT, part);
  k_ln<<<1200, 256, 0, stream>>>(part, bv, lng, lnb, out);
}

// Round 12
// 213.968 us; speedup vs baseline: 1.7481x; 1.5056x over previous
//
#include <hip/hip_runtime.h>

typedef __bf16 bf16;
typedef __bf16 b16x8 __attribute__((ext_vector_type(8)));
typedef __bf16 b16x4 __attribute__((ext_vector_type(4)));
typedef float  f32x4 __attribute__((ext_vector_type(4)));

#define BN_TOT 1200
#define PROWS  1216    // padded row count (multiple of 64)
#define NCOL   53248   // G*(PW+SP) = 4*13312
#define QD     256

// ---------------------------------------------------------------------------
// K_pre: fused preprocessing, blockIdx-partitioned:
//   [0,512)   : W_v transpose -> WvT bf16
//   [512,664) : query f32 -> bf16 padded to 1216 rows
// (mb GEMM moved into k_params as MFMA blocks 416..418)
// ---------------------------------------------------------------------------
__global__ __launch_bounds__(256) void k_pre(const float* __restrict__ Wv,
                                             bf16* __restrict__ WvT,
                                             const float* __restrict__ qry,
                                             bf16* __restrict__ qbf) {
  const int b = blockIdx.x;
  const int tid = threadIdx.x;
  if (b < 512) {
    __shared__ float t[64][65];
    const int kb = (b & 127) * 64, cb = (b >> 7) * 64;
    for (int i = 0; i < 16; ++i) {
      int idx = i * 256 + tid;
      int kk = idx >> 6, cc = idx & 63;
      t[kk][cc] = Wv[(size_t)(kb + kk) * 256 + cb + cc];
    }
    __syncthreads();
    for (int i = 0; i < 16; ++i) {
      int idx = i * 256 + tid;
      int cc = idx >> 6, kk = idx & 63;
      WvT[(size_t)(cb + cc) * 8192 + kb + kk] = (bf16)t[kk][cc];
    }
  } else {
    int gid = (b - 512) * 256 + tid;
    int base = gid * 8;
    int row = base >> 8;
    b16x8 o;
#pragma unroll
    for (int i = 0; i < 8; ++i) o[i] = (bf16)0.f;
    if (row < BN_TOT) {
      float4 a0 = *(const float4*)&qry[base];
      float4 a1 = *(const float4*)&qry[base + 4];
      o[0] = (bf16)a0.x; o[1] = (bf16)a0.y; o[2] = (bf16)a0.z; o[3] = (bf16)a0.w;
      o[4] = (bf16)a1.x; o[5] = (bf16)a1.y; o[6] = (bf16)a1.z; o[7] = (bf16)a1.w;
    }
    *(b16x8*)&qbf[base] = o;
  }
}

// ---------------------------------------------------------------------------
// K1: blocks [0,416):  P  = bf16(query @ W_gen  + b_gen)   (1216 x 53248)
//     blocks [416,419): mb = f32 (query @ W_bias + b_bias) (1200 x 384)
// Same verified A-pipeline for all blocks (double-buffered global_load_lds,
// one barrier per rc); per-block-uniform source/epilogue selection.
// ---------------------------------------------------------------------------
__global__ __launch_bounds__(256) void k_params(const bf16* __restrict__ qbf,
                                                const float* __restrict__ Wg,
                                                const float* __restrict__ bg,
                                                const float* __restrict__ Wb,
                                                const float* __restrict__ bb,
                                                float* __restrict__ mbw,
                                                bf16* __restrict__ P) {
  __shared__ __align__(16) bf16 lds[2 * 64 * 256];   // 64 KB A double-buffer

  const int tid  = threadIdx.x;
  const int wave = tid >> 6, lane = tid & 63;
  const int l15  = lane & 15, lhi = lane >> 4;

  const bool is_mb = (blockIdx.x >= 416);
  const int  col0  = (is_mb ? (blockIdx.x - 416) : blockIdx.x) * 128;
  const float* Wsrc = is_mb ? Wb : Wg;
  const float* bsrc = is_mb ? bb : bg;
  const int    ldw  = is_mb ? 384 : NCOL;

  // B fragments + bias, straight from global (one-time, no LDS, no sync)
  b16x8 bfrag[2][8];
  float bcol[2];
#pragma unroll
  for (int nt = 0; nt < 2; ++nt) {
    int col = col0 + wave * 32 + nt * 16 + l15;
#pragma unroll
    for (int kk = 0; kk < 8; ++kk)
#pragma unroll
      for (int j = 0; j < 8; ++j)
        bfrag[nt][kk][j] = (bf16)Wsrc[(size_t)(kk * 32 + lhi * 8 + j) * ldw + col];
    bcol[nt] = bsrc[col];
  }

  // ---- K-loop over 19 row-tiles (verified structure, unchanged) ----
  const char* qb = (const char*)qbf;
#define STAGE_A(b, rc)                                                         \
  {                                                                            \
    const char* s0 = qb + (size_t)(rc) * 64 * 512;                             \
    _Pragma("unroll")                                                          \
    for (int i = 0; i < 8; ++i) {                                              \
      int c = i * 256 + wave * 64 + lane;                                      \
      int r = c >> 5;                                                          \
      int boff = ((c & 31) << 4) ^ ((r & 7) << 4);                             \
      const void* src = (const void*)(s0 + r * 512 + boff);                    \
      bf16* dst = &lds[(b) * 16384 + (size_t)(i * 256 + wave * 64) * 8];       \
      __builtin_amdgcn_global_load_lds(                                        \
          (const __attribute__((address_space(1))) void*)src,                  \
          (__attribute__((address_space(3))) void*)dst, 16, 0, 0);             \
    }                                                                          \
  }

  STAGE_A(0, 0);
  __syncthreads();   // drain prologue staging

  for (int rc = 0; rc < 19; ++rc) {
    int cur = rc & 1;
    if (rc + 1 < 19) STAGE_A(cur ^ 1, rc + 1);   // prefetch flies under compute

    const bf16* At = &lds[cur * 16384];
    int r0 = rc * 64;
    f32x4 acc[4][2] = {};
#pragma unroll
    for (int kk = 0; kk < 8; ++kk)
#pragma unroll
      for (int mt = 0; mt < 4; ++mt) {
        int row = mt * 16 + l15;
        int coff = (kk * 32 + lhi * 8) ^ ((l15 & 7) << 3);
        b16x8 af = *(const b16x8*)&At[row * 256 + coff];
        acc[mt][0] = __builtin_amdgcn_mfma_f32_16x16x32_bf16(af, bfrag[0][kk], acc[mt][0], 0, 0, 0);
        acc[mt][1] = __builtin_amdgcn_mfma_f32_16x16x32_bf16(af, bfrag[1][kk], acc[mt][1], 0, 0, 0);
      }
    if (!is_mb) {
#pragma unroll
      for (int mt = 0; mt < 4; ++mt) {
        int rbase = r0 + mt * 16 + lhi * 4;
#pragma unroll
        for (int nt = 0; nt < 2; ++nt) {
          size_t cg = (size_t)col0 + wave * 32 + nt * 16 + l15;
          bf16* pp = &P[(size_t)rbase * NCOL + cg];
#pragma unroll
          for (int r = 0; r < 4; ++r)
            pp[(size_t)r * NCOL] = (bf16)(acc[mt][nt][r] + bcol[nt]);
        }
      }
    } else {
#pragma unroll
      for (int mt = 0; mt < 4; ++mt) {
        int rbase = r0 + mt * 16 + lhi * 4;
#pragma unroll
        for (int nt = 0; nt < 2; ++nt) {
          int cg = col0 + wave * 32 + nt * 16 + l15;
#pragma unroll
          for (int r = 0; r < 4; ++r) {
            int row = rbase + r;
            if (row < BN_TOT)
              mbw[(size_t)row * 384 + cg] = acc[mt][nt][r] + bcol[nt];
          }
        }
      }
    }
    __syncthreads();   // prefetch complete + buffer safe to overwrite
  }
#undef STAGE_A
}

// ---------------------------------------------------------------------------
// K2: per-(bn,g) cascade mix. R9-verbatim body.
// ---------------------------------------------------------------------------
__global__ __launch_bounds__(256, 4) void k_mix(const float* __restrict__ x,
                                                const bf16* __restrict__ P,
                                                const float* __restrict__ mb,
                                                bf16* __restrict__ H) {
  __shared__ __align__(16) bf16 h1T[64 * 296];   // [d][p], 37.9 KB

  const int blk = blockIdx.x;
  const int bn = blk >> 2, g = blk & 3;
  const int tid = threadIdx.x;
  const int wave = tid >> 6, lane = tid & 63;
  const int l15 = lane & 15, lhi = lane >> 4;

  const size_t pb = (size_t)bn * NCOL + g * 13312;
  const float* mbp = mb + (size_t)bn * 384 + g * 96;

  // M fragments (B-operand [k=c][n=d]) direct from P, scalar gather
  b16x8 mfrag[4][2];
  float mbv[4];
#pragma unroll
  for (int nt = 0; nt < 4; ++nt) {
    int d = nt * 16 + l15;
    mbv[nt] = mbp[d];
#pragma unroll
    for (int kk = 0; kk < 2; ++kk) {
      const bf16* mp = &P[pb + (size_t)(kk * 32 + lhi * 8) * 64 + d];
#pragma unroll
      for (int j = 0; j < 8; ++j) mfrag[nt][kk][j] = mp[(size_t)j * 64];
    }
  }

  // S fragments prefetched now (independent of h1)
  const int mt2 = wave >> 1;
  const int ntb = (wave & 1) * 2;
  const bf16* Sp = &P[pb + 4096];
  b16x8 sfrag[9];
#pragma unroll
  for (int kk = 0; kk < 9; ++kk)
    sfrag[kk] = *(const b16x8*)&Sp[(size_t)(mt2 * 16 + l15) * 288 + kk * 32 + lhi * 8];

  // MFMA1: h1 = relu(x @ M * 0.125 + M_b), A = x streamed from HBM
  const float* xp0 = &x[((size_t)bn * 4 + g) * 18432];
#pragma unroll
  for (int m0 = 0; m0 < 5; ++m0) {
    int mt = wave + m0 * 4;
    if (mt < 18) {
      f32x4 acc[4] = {};
#pragma unroll
      for (int kk = 0; kk < 2; ++kk) {
        const float* xp = xp0 + (mt * 16 + l15) * 64 + kk * 32 + lhi * 8;
        float4 a0 = *(const float4*)xp;
        float4 a1 = *(const float4*)(xp + 4);
        b16x8 af;
        af[0] = (bf16)a0.x; af[1] = (bf16)a0.y; af[2] = (bf16)a0.z; af[3] = (bf16)a0.w;
        af[4] = (bf16)a1.x; af[5] = (bf16)a1.y; af[6] = (bf16)a1.z; af[7] = (bf16)a1.w;
#pragma unroll
        for (int nt = 0; nt < 4; ++nt)
          acc[nt] = __builtin_amdgcn_mfma_f32_16x16x32_bf16(af, mfrag[nt][kk], acc[nt], 0, 0, 0);
      }
#pragma unroll
      for (int nt = 0; nt < 4; ++nt) {
        int d = nt * 16 + l15;
        b16x4 hv;
#pragma unroll
        for (int r = 0; r < 4; ++r) {
          float v = acc[nt][r] * 0.125f + mbv[nt];   // /TEMPER then +M_b
          hv[r] = (bf16)(v > 0.f ? v : 0.f);
        }
        *(b16x4*)&h1T[d * 296 + mt * 16 + lhi * 4] = hv;
      }
    }
  }
  __syncthreads();

  // S_b gathered here: consumed only at the H-store, latency hides under MFMA2
  float sbv[4];
#pragma unroll
  for (int r = 0; r < 4; ++r) sbv[r] = mbp[64 + mt2 * 16 + lhi * 4 + r];

  // MFMA2: h2 = relu(S @ h1 + S_b), S already in registers
  f32x4 acc2[2] = {};
#pragma unroll
  for (int kk = 0; kk < 9; ++kk) {
#pragma unroll
    for (int t = 0; t < 2; ++t) {
      b16x8 bfv = *(const b16x8*)&h1T[((ntb + t) * 16 + l15) * 296 + kk * 32 + lhi * 8];
      acc2[t] = __builtin_amdgcn_mfma_f32_16x16x32_bf16(sfrag[kk], bfv, acc2[t], 0, 0, 0);
    }
  }
  bf16* Hp = H + (size_t)bn * 8192 + g * 64;       // H[bn][o][g][c]
#pragma unroll
  for (int r = 0; r < 4; ++r) {
    int o = mt2 * 16 + lhi * 4 + r;
#pragma unroll
    for (int t = 0; t < 2; ++t) {
      float v = acc2[t][r] + sbv[r];
      Hp[o * 256 + (ntb + t) * 16 + l15] = (bf16)(v > 0.f ? v : 0.f);
    }
  }
}

// ---------------------------------------------------------------------------
// K3: part[kz] = H[:, kz*512:+512] @ W_vT^T   (split-K=16, fp32 partials)
// R6-verbatim: LDS-free, sync-free.
// ---------------------------------------------------------------------------
__global__ __launch_bounds__(256) void k_out(const bf16* __restrict__ H,
                                             const bf16* __restrict__ WvT,
                                             float* __restrict__ part) {
  const int tid = threadIdx.x;
  const int wave = tid >> 6, lane = tid & 63;
  const int l15 = lane & 15, lhi = lane >> 4;
  const int r0 = blockIdx.x * 64;
  const int k0 = blockIdx.y * 512;

  f32x4 acc[4][4] = {};
  for (int it = 0; it < 8; ++it) {
    int kb = k0 + it * 64;
    b16x8 bfv[2][4], afv[2][4];
#pragma unroll
    for (int kk = 0; kk < 2; ++kk)
#pragma unroll
      for (int nt = 0; nt < 4; ++nt)
        bfv[kk][nt] = *(const b16x8*)&WvT[(size_t)(wave * 64 + nt * 16 + l15) * 8192 + kb + kk * 32 + lhi * 8];
#pragma unroll
    for (int kk = 0; kk < 2; ++kk)
#pragma unroll
      for (int mt = 0; mt < 4; ++mt)
        afv[kk][mt] = *(const b16x8*)&H[(size_t)(r0 + mt * 16 + l15) * 8192 + kb + kk * 32 + lhi * 8];
#pragma unroll
    for (int kk = 0; kk < 2; ++kk)
#pragma unroll
      for (int mt = 0; mt < 4; ++mt)
#pragma unroll
        for (int nt = 0; nt < 4; ++nt)
          acc[mt][nt] = __builtin_amdgcn_mfma_f32_16x16x32_bf16(afv[kk][mt], bfv[kk][nt], acc[mt][nt], 0, 0, 0);
  }
  const size_t pbase = (size_t)blockIdx.y * PROWS * 256;
#pragma unroll
  for (int mt = 0; mt < 4; ++mt)
#pragma unroll
    for (int nt = 0; nt < 4; ++nt) {
      int col = wave * 64 + nt * 16 + l15;
#pragma unroll
      for (int r = 0; r < 4; ++r) {
        int row = r0 + mt * 16 + lhi * 4 + r;
        part[pbase + (size_t)row * 256 + col] = acc[mt][nt][r];
      }
    }
}

// ---------------------------------------------------------------------------
// K4: out = LayerNorm(sum_kz part + b_v) * ln_g + ln_b   (R6-verbatim)
// ---------------------------------------------------------------------------
__global__ __launch_bounds__(256) void k_ln(const float* __restrict__ part,
                                            const float* __restrict__ bv,
                                            const float* __restrict__ lng,
                                            const float* __restrict__ lnb,
                                            float* __restrict__ out) {
  __shared__ float red[8];
  const int row = blockIdx.x, c = threadIdx.x;
  const int wave = c >> 6, lane = c & 63;
  float v = bv[c];
  for (int kz = 0; kz < 16; ++kz)
    v += part[((size_t)kz * PROWS + row) * 256 + c];
  float s = v;
  for (int off = 32; off > 0; off >>= 1) s += __shfl_xor(s, off);
  if (lane == 0) red[wave] = s;
  __syncthreads();
  float mean = (red[0] + red[1] + red[2] + red[3]) * (1.0f / 256.0f);
  float d = v - mean;
  float q = d * d;
  for (int off = 32; off > 0; off >>= 1) q += __shfl_xor(q, off);
  if (lane == 0) red[4 + wave] = q;
  __syncthreads();
  float var = (red[4] + red[5] + red[6] + red[7]) * (1.0f / 256.0f);
  out[(size_t)row * 256 + c] = d * rsqrtf(var + 1e-5f) * lng[c] + lnb[c];
}

// ---------------------------------------------------------------------------
extern "C" void kernel_launch(void* const* d_in, const int* in_sizes, int n_in,
                              void* d_out, int out_size, void* d_ws, size_t ws_size,
                              hipStream_t stream) {
  const float* x   = (const float*)d_in[0];
  const float* qry = (const float*)d_in[1];
  const float* Wg  = (const float*)d_in[2];
  const float* bg  = (const float*)d_in[3];
  const float* Wb  = (const float*)d_in[4];
  const float* bb  = (const float*)d_in[5];
  const float* Wv  = (const float*)d_in[6];
  const float* bv  = (const float*)d_in[7];
  const float* lng = (const float*)d_in[8];
  const float* lnb = (const float*)d_in[9];
  float* out = (float*)d_out;

  // ws layout (bytes):
  char* ws = (char*)d_ws;
  bf16*  P    = (bf16*) (ws + 0);           // params bf16: 1216*53248*2 = 129,499,136
  bf16*  H    = (bf16*) (ws + 129499136);   // h2 bf16:     1216*8192*2  = 19,922,944
  float* mbw  = (float*)(ws + 149422080);   // mix bias:    1200*384*4   = 1,843,200
  bf16*  WvT  = (bf16*) (ws + 151265280);   // W_v^T bf16:  256*8192*2   = 4,194,304
  float* part = (float*)(ws + 155459584);   // splitK:      16*1216*256*4 = 19,922,944
  bf16*  qbf  = (bf16*) (ws + 155459584);   // aliased over part (dead before k_out)

  k_pre<<<664, 256, 0, stream>>>(Wv, WvT, qry, qbf);
  k_params<<<419, 256, 0, stream>>>(qbf, Wg, bg, Wb, bb, mbw, P);
  k_mix<<<4800, 256, 0, stream>>>(x, P, mbw, H);
  k_out<<<dim3(19, 16), 256, 0, stream>>>(H, WvT, part);
  k_ln<<<1200, 256, 0, stream>>>(part, bv, lng, lnb, out);
}